// Round 7
// baseline (910.939 us; speedup 1.0000x reference)
//
#include <hip/hip_runtime.h>

// Problem dims (fixed by reference setup_inputs)
constexpr int B = 64, T = 256, I = 2048, H = 4096, O = 1024;

#define DECAY 0.9f
#define THRESH 1.0f

// ---------------------------------------------------------------------------
// DIAGNOSTIC ROUND (R7): every bulk kernel's body runs REP=8 times inside the
// kernel (idempotent: each rep re-computes and re-stores identical values;
// reduce_part stores only on the last rep). Purpose:
//  (a) each kernel's dur_us becomes 8x -> rises above the 77us harness
//      poison-fills into the rocprof top-5, giving per-kernel counters for
//      the first time this session;
//  (b) aggregate dur = fixed_overhead + 8*S vs R5's fixed + S = 284.6us
//      separates the fixed harness floor from real kernel work S.
// asm volatile memory clobbers per rep prevent cross-rep load CSE; keep-alive
// asm prevents DCE of non-storing reps. REVERT REP->1 NEXT ROUND.
// ---------------------------------------------------------------------------
#define REP 8

typedef __attribute__((ext_vector_type(8))) __bf16 bf16x8;
typedef __attribute__((ext_vector_type(4))) float f32x4;

// ---------------------------------------------------------------------------
// fp32 -> (hi, lo) bf16 split by truncation. a ~= hi + lo with |err| <~ 2^-16 |a|
// ---------------------------------------------------------------------------
__device__ inline void split_bf16(float a, unsigned short& hi, unsigned short& lo) {
    unsigned int u = __float_as_uint(a);
    hi = (unsigned short)(u >> 16);
    float fhi = __uint_as_float(u & 0xffff0000u);
    lo = (unsigned short)(__float_as_uint(a - fhi) >> 16);
}

// ---------------------------------------------------------------------------
// Kernel 1: xbar = (1/B) sum_b x[b]  -> write bf16 hi/lo planes [T,I]
// ---------------------------------------------------------------------------
__global__ __launch_bounds__(256) void batch_reduce(const float* __restrict__ x,
                                                    unsigned short* __restrict__ xh,
                                                    unsigned short* __restrict__ xl) {
    const int idx = blockIdx.x * 256 + threadIdx.x;  // float4 index in [T*I/4)
    const float4* x4 = (const float4*)x;
    const int stride4 = (T * I) / 4;
    for (int rep = 0; rep < REP; ++rep) {
        asm volatile("" ::: "memory");
        float4 acc = {0.f, 0.f, 0.f, 0.f};
#pragma unroll 16
        for (int b = 0; b < B; ++b) {
            float4 v = x4[idx + (size_t)b * stride4];
            acc.x += v.x; acc.y += v.y; acc.z += v.z; acc.w += v.w;
        }
        const float s = 1.0f / (float)B;
        float a[4] = {acc.x * s, acc.y * s, acc.z * s, acc.w * s};
        unsigned short hi[4], lo[4];
#pragma unroll
        for (int j = 0; j < 4; ++j) split_bf16(a[j], hi[j], lo[j]);
        uint2 ph, pl;
        ph.x = (unsigned int)hi[0] | ((unsigned int)hi[1] << 16);
        ph.y = (unsigned int)hi[2] | ((unsigned int)hi[3] << 16);
        pl.x = (unsigned int)lo[0] | ((unsigned int)lo[1] << 16);
        pl.y = (unsigned int)lo[2] | ((unsigned int)lo[3] << 16);
        ((uint2*)xh)[idx] = ph;
        ((uint2*)xl)[idx] = pl;
    }
}

// ---------------------------------------------------------------------------
// Kernel 2 (fallback path only): currents[t,h] = b_in[h]
// ---------------------------------------------------------------------------
__global__ __launch_bounds__(256) void cur_init(const float* __restrict__ b_in,
                                                float* __restrict__ cur) {
    const int idx = blockIdx.x * 256 + threadIdx.x;
    const int h4 = idx & (H / 4 - 1);
    ((float4*)cur)[idx] = ((const float4*)b_in)[h4];
}

// ---------------------------------------------------------------------------
// Kernel 3: currents += xbar @ W_in  via bf16 hi/lo 3-pass MFMA (fp32-accurate)
// Round-0 configuration: BM=256, BN=32, BK=32, KSPLIT=4, grid (H/BN, KSPLIT).
// ---------------------------------------------------------------------------
#define BN 32
#define BK 32
#define KSPLIT 4
#define KCHUNK (I / KSPLIT)  // 512

__global__ __launch_bounds__(256) void gemm_in(const unsigned short* __restrict__ xh,
                                               const unsigned short* __restrict__ xl,
                                               const float* __restrict__ Wi,   // [I,H]
                                               float* __restrict__ dst,
                                               int useAtomic) {
    __shared__ unsigned short BtH[BN][BK + 8];  // [n][k], row stride 40 (80 B)
    __shared__ unsigned short BtL[BN][BK + 8];

    const int tid = threadIdx.x;
    const int n0 = blockIdx.x * BN;
    const int split = blockIdx.y;
    const int kBeg = split * KCHUNK;
    const int wave = tid >> 6, lane = tid & 63;
    const int quad = lane >> 4, l16 = lane & 15;
    const int m0 = wave * 64;  // each wave owns a 64-row m-strip (4 m-tiles)

    const int sn = tid & 31;          // staging: n within tile
    const int sk = (tid >> 5) << 2;   // staging: k base (0,4,...,28)

    for (int rep = 0; rep < REP; ++rep) {
        asm volatile("" ::: "memory");
        f32x4 acc[4][2];
#pragma unroll
        for (int mi = 0; mi < 4; ++mi)
#pragma unroll
            for (int ni = 0; ni < 2; ++ni) acc[mi][ni] = (f32x4){0.f, 0.f, 0.f, 0.f};

        for (int k0 = kBeg; k0 < kBeg + KCHUNK; k0 += BK) {
            // --- global loads (issued before barrier; overlap with prev compute) ---
            const float* src = &Wi[(size_t)(k0 + sk) * H + n0 + sn];
            float v0 = src[0], v1 = src[(size_t)H], v2 = src[(size_t)2 * H], v3 = src[(size_t)3 * H];

            bf16x8 aH[4], aL[4];
#pragma unroll
            for (int mi = 0; mi < 4; ++mi) {
                const size_t arow = (size_t)(m0 + mi * 16 + l16) * I + k0 + quad * 8;
                aH[mi] = *(const bf16x8*)(xh + arow);
                aL[mi] = *(const bf16x8*)(xl + arow);
            }

            unsigned short h0, h1, h2, h3, l0, l1, l2, l3;
            split_bf16(v0, h0, l0); split_bf16(v1, h1, l1);
            split_bf16(v2, h2, l2); split_bf16(v3, h3, l3);

            __syncthreads();  // previous iteration's LDS readers done
            uint2 ph, pl;
            ph.x = (unsigned int)h0 | ((unsigned int)h1 << 16);
            ph.y = (unsigned int)h2 | ((unsigned int)h3 << 16);
            pl.x = (unsigned int)l0 | ((unsigned int)l1 << 16);
            pl.y = (unsigned int)l2 | ((unsigned int)l3 << 16);
            *(uint2*)&BtH[sn][sk] = ph;
            *(uint2*)&BtL[sn][sk] = pl;
            __syncthreads();

            bf16x8 bH[2], bL[2];
#pragma unroll
            for (int ni = 0; ni < 2; ++ni) {
                bH[ni] = *(const bf16x8*)&BtH[ni * 16 + l16][quad * 8];
                bL[ni] = *(const bf16x8*)&BtL[ni * 16 + l16][quad * 8];
            }
#pragma unroll
            for (int mi = 0; mi < 4; ++mi)
#pragma unroll
                for (int ni = 0; ni < 2; ++ni) {
                    acc[mi][ni] = __builtin_amdgcn_mfma_f32_16x16x32_bf16(aL[mi], bH[ni], acc[mi][ni], 0, 0, 0);
                    acc[mi][ni] = __builtin_amdgcn_mfma_f32_16x16x32_bf16(aH[mi], bL[ni], acc[mi][ni], 0, 0, 0);
                    acc[mi][ni] = __builtin_amdgcn_mfma_f32_16x16x32_bf16(aH[mi], bH[ni], acc[mi][ni], 0, 0, 0);
                }
        }

        // epilogue: C/D layout col=lane&15, row=quad*4+reg (verified m89/m91)
        float* base = useAtomic ? dst : dst + (size_t)split * T * H;
#pragma unroll
        for (int mi = 0; mi < 4; ++mi)
#pragma unroll
            for (int ni = 0; ni < 2; ++ni) {
                const int h = n0 + ni * 16 + l16;
#pragma unroll
                for (int r = 0; r < 4; ++r) {
                    const int m = m0 + mi * 16 + quad * 4 + r;
                    if (useAtomic) atomicAdd(&base[(size_t)m * H + h], acc[mi][ni][r]);
                    else           base[(size_t)m * H + h] = acc[mi][ni][r];
                }
            }
        if (useAtomic) break;  // atomic path is NOT idempotent: single rep
    }
}

// ---------------------------------------------------------------------------
// Kernel 4: fold split-K partials + bias into plane 0 (store only on last rep;
// earlier reps kept alive via asm, loads re-issued via memory clobber).
// ---------------------------------------------------------------------------
__global__ __launch_bounds__(256) void reduce_part(float* __restrict__ part,
                                                   const float* __restrict__ b_in,
                                                   int nsplit) {
    const int idx = blockIdx.x * 256 + threadIdx.x;  // float4 idx over T*H/4
    const int h4 = idx & (H / 4 - 1);
    const int plane4 = T * H / 4;
    for (int rep = 0; rep < REP; ++rep) {
        asm volatile("" ::: "memory");
        float4 s = ((const float4*)b_in)[h4];
        for (int sp = 0; sp < nsplit; ++sp) {
            float4 v = ((const float4*)part)[(size_t)sp * plane4 + idx];
            s.x += v.x; s.y += v.y; s.z += v.z; s.w += v.w;
        }
        if (rep == REP - 1) {
            ((float4*)part)[idx] = s;
        } else {
            asm volatile("" :: "v"(s.x), "v"(s.y), "v"(s.z), "v"(s.w));
        }
    }
}

// ---------------------------------------------------------------------------
// Kernel 5: LIF scan over T. One thread per h (hard parallelism cap H=4096).
// ---------------------------------------------------------------------------
__global__ __launch_bounds__(64) void lif_scan(const float* __restrict__ cur, // [T,H]
                                               const float* __restrict__ m0v, // [H]
                                               float* __restrict__ agg) {     // [H]
    const int h = blockIdx.x * 64 + threadIdx.x;
    for (int rep = 0; rep < REP; ++rep) {
        asm volatile("" ::: "memory");
        float m = m0v[h];
        float cnt = 0.f;
        float buf[2][32];
#pragma unroll
        for (int j = 0; j < 32; ++j) buf[0][j] = cur[(size_t)j * H + h];
#pragma unroll
        for (int b = 0; b < 8; ++b) {
            if (b + 1 < 8) {
#pragma unroll
                for (int j = 0; j < 32; ++j)
                    buf[(b + 1) & 1][j] = cur[(size_t)((b + 1) * 32 + j) * H + h];
            }
#pragma unroll
            for (int j = 0; j < 32; ++j) {
                m = DECAY * m + buf[b & 1][j];
                if (m > THRESH) { cnt += 1.f; m = 0.f; }
            }
        }
        agg[h] = cnt * (1.0f / (float)T);
    }
}

// ---------------------------------------------------------------------------
// Kernel 6: out_part[hy][o] = sum_{h in hy-block} agg[h] * Wout[h][o]
// ---------------------------------------------------------------------------
__global__ __launch_bounds__(256) void out_gemv(const float* __restrict__ agg,
                                                const float* __restrict__ Wout,  // [H,O]
                                                float* __restrict__ out_part) {  // [H/64, O]
    const int o = blockIdx.x * 256 + threadIdx.x;
    const int hy = blockIdx.y;
    const int h0 = hy * 64;
    for (int rep = 0; rep < REP; ++rep) {
        asm volatile("" ::: "memory");
        float s = 0.f;
#pragma unroll 8
        for (int hh = h0; hh < h0 + 64; ++hh) {
            s += agg[hh] * Wout[(size_t)hh * O + o];
        }
        out_part[(size_t)hy * O + o] = s;
    }
}

// ---------------------------------------------------------------------------
// Kernel 7: out[o] = b_out[o] + sum_hy out_part[hy][o]   (256 KB, L2-hot)
// ---------------------------------------------------------------------------
__global__ __launch_bounds__(256) void out_final(const float* __restrict__ out_part,
                                                 const float* __restrict__ b_out,
                                                 float* __restrict__ out) {
    const int o = blockIdx.x * 256 + threadIdx.x;
    float s = b_out[o];
#pragma unroll 8
    for (int hy = 0; hy < H / 64; ++hy) {
        s += out_part[(size_t)hy * O + o];
    }
    out[o] = s;
}

// ---------------------------------------------------------------------------
extern "C" void kernel_launch(void* const* d_in, const int* in_sizes, int n_in,
                              void* d_out, int out_size, void* d_ws, size_t ws_size,
                              hipStream_t stream) {
    const float* x     = (const float*)d_in[0];
    const float* W_in  = (const float*)d_in[1];
    const float* b_in  = (const float*)d_in[2];
    const float* W_out = (const float*)d_in[3];
    const float* b_out = (const float*)d_in[4];
    const float* m0    = (const float*)d_in[5];
    float* out = (float*)d_out;

    // ws: xbar_hi [T*I u16] | xbar_lo [T*I u16] | agg [H f32]
    //     | part [KSPLIT*T*H f32] | out_part [(H/64)*O f32]
    unsigned short* xh = (unsigned short*)d_ws;
    unsigned short* xl = xh + (size_t)T * I;
    float* agg  = (float*)(xl + (size_t)T * I);
    float* part = agg + H;
    float* out_part = part + (size_t)KSPLIT * T * H;

    const size_t need = (size_t)2 * T * I * 2 + (size_t)H * 4
                      + (size_t)KSPLIT * T * H * 4 + (size_t)(H / 64) * O * 4;
    const int fits = (ws_size >= need) ? 1 : 0;  // ws_size constant -> same path every launch

    // 1) batch mean -> bf16 hi/lo planes
    batch_reduce<<<(T * I / 4) / 256, 256, 0, stream>>>(x, xh, xl);

    dim3 g2(H / BN, KSPLIT);
    if (fits) {
        // 2) MFMA GEMM into split-K partial planes (plain stores)
        gemm_in<<<g2, 256, 0, stream>>>(xh, xl, W_in, part, 0);
        // 3) fold partials + bias into plane 0
        reduce_part<<<(T * H / 4) / 256, 256, 0, stream>>>(part, b_in, KSPLIT);
    } else {
        // fallback (small ws): atomic accumulation into a single bias-primed plane
        cur_init<<<(T * H / 4) / 256, 256, 0, stream>>>(b_in, part);
        gemm_in<<<g2, 256, 0, stream>>>(xh, xl, W_in, part, 1);
    }

    // 4) LIF scan over T -> agg[h]
    lif_scan<<<H / 64, 64, 0, stream>>>(part, m0, agg);

    // 5) out_part[hy] = agg-slice @ W_out-slice   (no atomics)
    dim3 g4(O / 256, H / 64);
    out_gemv<<<g4, 256, 0, stream>>>(agg, W_out, out_part);

    // 6) out = b_out + sum_hy out_part[hy]
    out_final<<<O / 256, 256, 0, stream>>>(out_part, b_out, out);
}

// Round 8
// 279.655 us; speedup vs baseline: 3.2574x; 3.2574x over previous
//
#include <hip/hip_runtime.h>

// Problem dims (fixed by reference setup_inputs)
constexpr int B = 64, T = 256, I = 2048, H = 4096, O = 1024;

#define DECAY 0.9f
#define THRESH 1.0f

// ---------------------------------------------------------------------------
// SESSION LEDGER (R7 diagnostic, REP=8 in-kernel repeat):
//   t(gemm_in) ~= 40us/exec; MfmaUtil 13%, VALUBusy 13%, HBM 12%, Occ 20%
//     -> latency/stall-bound (2 barriers/tile + exposed ~900cy W_in HBM loads,
//        only 2 blocks/CU of TLP). Bank conflicts 786K/rep (stride-40 pad).
//   Sum of bulk kernels S ~= 89.5us; fixed floor ~= 190us (two ~77us 512MiB
//     workspace poison-fills + ~6 launch gaps) -> fixed floor masked all
//     aggregate A/Bs in R0-R5.
// R8: gemm_in restructured (depth-2 W prefetch, LDS dbuf w/ SINGLE barrier
//     per tile, BK+4 conflict-free padding). Numerics bitwise-identical
//     (same MFMA order, same KSPLIT=4 fold). Everything else untouched.
// ---------------------------------------------------------------------------

typedef __attribute__((ext_vector_type(8))) __bf16 bf16x8;
typedef __attribute__((ext_vector_type(4))) float f32x4;

// ---------------------------------------------------------------------------
// fp32 -> (hi, lo) bf16 split by truncation. a ~= hi + lo with |err| <~ 2^-16 |a|
// ---------------------------------------------------------------------------
__device__ inline void split_bf16(float a, unsigned short& hi, unsigned short& lo) {
    unsigned int u = __float_as_uint(a);
    hi = (unsigned short)(u >> 16);
    float fhi = __uint_as_float(u & 0xffff0000u);
    lo = (unsigned short)(__float_as_uint(a - fhi) >> 16);
}

// ---------------------------------------------------------------------------
// Kernel 1: xbar = (1/B) sum_b x[b]  -> write bf16 hi/lo planes [T,I]
// ~19-25us (HBM floor for its 134MB read). Leave alone.
// ---------------------------------------------------------------------------
__global__ __launch_bounds__(256) void batch_reduce(const float* __restrict__ x,
                                                    unsigned short* __restrict__ xh,
                                                    unsigned short* __restrict__ xl) {
    const int idx = blockIdx.x * 256 + threadIdx.x;  // float4 index in [T*I/4)
    const float4* x4 = (const float4*)x;
    const int stride4 = (T * I) / 4;
    float4 acc = {0.f, 0.f, 0.f, 0.f};
#pragma unroll 16
    for (int b = 0; b < B; ++b) {
        float4 v = x4[idx + (size_t)b * stride4];
        acc.x += v.x; acc.y += v.y; acc.z += v.z; acc.w += v.w;
    }
    const float s = 1.0f / (float)B;
    float a[4] = {acc.x * s, acc.y * s, acc.z * s, acc.w * s};
    unsigned short hi[4], lo[4];
#pragma unroll
    for (int j = 0; j < 4; ++j) split_bf16(a[j], hi[j], lo[j]);
    uint2 ph, pl;
    ph.x = (unsigned int)hi[0] | ((unsigned int)hi[1] << 16);
    ph.y = (unsigned int)hi[2] | ((unsigned int)hi[3] << 16);
    pl.x = (unsigned int)lo[0] | ((unsigned int)lo[1] << 16);
    pl.y = (unsigned int)lo[2] | ((unsigned int)lo[3] << 16);
    ((uint2*)xh)[idx] = ph;
    ((uint2*)xl)[idx] = pl;
}

// ---------------------------------------------------------------------------
// Kernel 2 (fallback path only): currents[t,h] = b_in[h]
// ---------------------------------------------------------------------------
__global__ __launch_bounds__(256) void cur_init(const float* __restrict__ b_in,
                                                float* __restrict__ cur) {
    const int idx = blockIdx.x * 256 + threadIdx.x;
    const int h4 = idx & (H / 4 - 1);
    ((float4*)cur)[idx] = ((const float4*)b_in)[h4];
}

// ---------------------------------------------------------------------------
// Kernel 3 (R8 rewrite): currents += xbar @ W_in, bf16 hi/lo 3-pass MFMA.
// R7 counters: 40us, all-pipes-idle latency-bound. Fixes:
//  (1) depth-2 W_in register prefetch (vA/vB): tile k+2's 4 HBM loads issued
//      right after tile k's values are consumed -> ~1.5-iter window (~850cy)
//      covers the ~900cy HBM latency that was fully exposed before.
//  (2) LDS double-buffer with ONE barrier per tile (was 2). Safe: a wave's
//      ds_reads of buf[p^1] drain before it reaches the next s_barrier
//      (compiler lgkmcnt before barrier); overwrite is 2 barriers later.
//  (3) BK+4 pad (row stride 36 u16 = 18 banks): 16-row b128 reads hit 16
//      distinct banks (stride-18 mod 32 cycle covers all), writes 2-way
//      (free). Old BK+8/stride-20 was 4-way on writes (786K conflicts/exec).
// Accumulation order unchanged -> bitwise-identical to R0/R5 (absmax 0.0).
// ---------------------------------------------------------------------------
#define BN 32
#define BK 32
#define KSPLIT 4
#define KCHUNK (I / KSPLIT)  // 512

__global__ __launch_bounds__(256) void gemm_in(const unsigned short* __restrict__ xh,
                                               const unsigned short* __restrict__ xl,
                                               const float* __restrict__ Wi,   // [I,H]
                                               float* __restrict__ dst,
                                               int useAtomic) {
    __shared__ unsigned short BtH[2][BN][BK + 4];  // [buf][n][k], row stride 36 u16
    __shared__ unsigned short BtL[2][BN][BK + 4];

    const int tid = threadIdx.x;
    const int n0 = blockIdx.x * BN;
    const int split = blockIdx.y;
    const int kBeg = split * KCHUNK;
    const int kEnd = kBeg + KCHUNK;
    const int wave = tid >> 6, lane = tid & 63;
    const int quad = lane >> 4, l16 = lane & 15;
    const int m0 = wave * 64;  // each wave owns a 64-row m-strip (4 m-tiles)

    const int sn = tid & 31;          // staging: n within tile
    const int sk = (tid >> 5) << 2;   // staging: k base (0,4,...,28)

    f32x4 acc[4][2];
#pragma unroll
    for (int mi = 0; mi < 4; ++mi)
#pragma unroll
        for (int ni = 0; ni < 2; ++ni) acc[mi][ni] = (f32x4){0.f, 0.f, 0.f, 0.f};

    // prologue: W_in tiles 0 and 1 in flight (vA = tile k0, vB = tile k0+BK)
    const float* pA = &Wi[(size_t)(kBeg + sk) * H + n0 + sn];
    const float* pB = pA + (size_t)BK * H;
    float vA0 = pA[0], vA1 = pA[(size_t)H], vA2 = pA[(size_t)2 * H], vA3 = pA[(size_t)3 * H];
    float vB0 = pB[0], vB1 = pB[(size_t)H], vB2 = pB[(size_t)2 * H], vB3 = pB[(size_t)3 * H];

    int p = 0;
    for (int k0 = kBeg; k0 < kEnd; k0 += 2 * BK) {
        // ================= sub-iter A: tile k0 (W regs vA) =================
        {
            // A-fragments for this tile (L2-hot; window = split+write+barrier)
            bf16x8 aH[4], aL[4];
#pragma unroll
            for (int mi = 0; mi < 4; ++mi) {
                const size_t arow = (size_t)(m0 + mi * 16 + l16) * I + k0 + quad * 8;
                aH[mi] = *(const bf16x8*)(xh + arow);
                aL[mi] = *(const bf16x8*)(xl + arow);
            }
            // consume vA now, then immediately re-issue vA for tile k0+2*BK
            unsigned short h0, h1, h2, h3, l0, l1, l2, l3;
            split_bf16(vA0, h0, l0); split_bf16(vA1, h1, l1);
            split_bf16(vA2, h2, l2); split_bf16(vA3, h3, l3);
            pA = (k0 + 2 * BK < kEnd) ? pA + (size_t)(2 * BK) * H : pA;
            vA0 = pA[0]; vA1 = pA[(size_t)H]; vA2 = pA[(size_t)2 * H]; vA3 = pA[(size_t)3 * H];

            uint2 ph, pl;
            ph.x = (unsigned int)h0 | ((unsigned int)h1 << 16);
            ph.y = (unsigned int)h2 | ((unsigned int)h3 << 16);
            pl.x = (unsigned int)l0 | ((unsigned int)l1 << 16);
            pl.y = (unsigned int)l2 | ((unsigned int)l3 << 16);
            *(uint2*)&BtH[p][sn][sk] = ph;
            *(uint2*)&BtL[p][sn][sk] = pl;
            __syncthreads();  // single barrier: buf[p] now fully written

            bf16x8 bH[2], bL[2];
#pragma unroll
            for (int ni = 0; ni < 2; ++ni) {
                bH[ni] = *(const bf16x8*)&BtH[p][ni * 16 + l16][quad * 8];
                bL[ni] = *(const bf16x8*)&BtL[p][ni * 16 + l16][quad * 8];
            }
#pragma unroll
            for (int mi = 0; mi < 4; ++mi)
#pragma unroll
                for (int ni = 0; ni < 2; ++ni) {
                    acc[mi][ni] = __builtin_amdgcn_mfma_f32_16x16x32_bf16(aL[mi], bH[ni], acc[mi][ni], 0, 0, 0);
                    acc[mi][ni] = __builtin_amdgcn_mfma_f32_16x16x32_bf16(aH[mi], bL[ni], acc[mi][ni], 0, 0, 0);
                    acc[mi][ni] = __builtin_amdgcn_mfma_f32_16x16x32_bf16(aH[mi], bH[ni], acc[mi][ni], 0, 0, 0);
                }
            p ^= 1;
        }
        // ================= sub-iter B: tile k0+BK (W regs vB) ==============
        {
            const int k1 = k0 + BK;
            bf16x8 aH[4], aL[4];
#pragma unroll
            for (int mi = 0; mi < 4; ++mi) {
                const size_t arow = (size_t)(m0 + mi * 16 + l16) * I + k1 + quad * 8;
                aH[mi] = *(const bf16x8*)(xh + arow);
                aL[mi] = *(const bf16x8*)(xl + arow);
            }
            unsigned short h0, h1, h2, h3, l0, l1, l2, l3;
            split_bf16(vB0, h0, l0); split_bf16(vB1, h1, l1);
            split_bf16(vB2, h2, l2); split_bf16(vB3, h3, l3);
            pB = (k1 + 2 * BK < kEnd) ? pB + (size_t)(2 * BK) * H : pB;
            vB0 = pB[0]; vB1 = pB[(size_t)H]; vB2 = pB[(size_t)2 * H]; vB3 = pB[(size_t)3 * H];

            uint2 ph, pl;
            ph.x = (unsigned int)h0 | ((unsigned int)h1 << 16);
            ph.y = (unsigned int)h2 | ((unsigned int)h3 << 16);
            pl.x = (unsigned int)l0 | ((unsigned int)l1 << 16);
            pl.y = (unsigned int)l2 | ((unsigned int)l3 << 16);
            *(uint2*)&BtH[p][sn][sk] = ph;
            *(uint2*)&BtL[p][sn][sk] = pl;
            __syncthreads();

            bf16x8 bH[2], bL[2];
#pragma unroll
            for (int ni = 0; ni < 2; ++ni) {
                bH[ni] = *(const bf16x8*)&BtH[p][ni * 16 + l16][quad * 8];
                bL[ni] = *(const bf16x8*)&BtL[p][ni * 16 + l16][quad * 8];
            }
#pragma unroll
            for (int mi = 0; mi < 4; ++mi)
#pragma unroll
                for (int ni = 0; ni < 2; ++ni) {
                    acc[mi][ni] = __builtin_amdgcn_mfma_f32_16x16x32_bf16(aL[mi], bH[ni], acc[mi][ni], 0, 0, 0);
                    acc[mi][ni] = __builtin_amdgcn_mfma_f32_16x16x32_bf16(aH[mi], bL[ni], acc[mi][ni], 0, 0, 0);
                    acc[mi][ni] = __builtin_amdgcn_mfma_f32_16x16x32_bf16(aH[mi], bH[ni], acc[mi][ni], 0, 0, 0);
                }
            p ^= 1;
        }
    }

    // epilogue: C/D layout col=lane&15, row=quad*4+reg (verified m89/m91)
    float* base = useAtomic ? dst : dst + (size_t)split * T * H;
#pragma unroll
    for (int mi = 0; mi < 4; ++mi)
#pragma unroll
        for (int ni = 0; ni < 2; ++ni) {
            const int h = n0 + ni * 16 + l16;
#pragma unroll
            for (int r = 0; r < 4; ++r) {
                const int m = m0 + mi * 16 + quad * 4 + r;
                if (useAtomic) atomicAdd(&base[(size_t)m * H + h], acc[mi][ni][r]);
                else           base[(size_t)m * H + h] = acc[mi][ni][r];
            }
        }
}

// ---------------------------------------------------------------------------
// Kernel 4: fold split-K partials + bias into plane 0 IN-PLACE (~12us, BW).
// ---------------------------------------------------------------------------
__global__ __launch_bounds__(256) void reduce_part(float* __restrict__ part,
                                                   const float* __restrict__ b_in,
                                                   int nsplit) {
    const int idx = blockIdx.x * 256 + threadIdx.x;  // float4 idx over T*H/4
    const int h4 = idx & (H / 4 - 1);
    float4 s = ((const float4*)b_in)[h4];
    const int plane4 = T * H / 4;
    for (int sp = 0; sp < nsplit; ++sp) {
        float4 v = ((const float4*)part)[(size_t)sp * plane4 + idx];
        s.x += v.x; s.y += v.y; s.z += v.z; s.w += v.w;
    }
    ((float4*)part)[idx] = s;
}

// ---------------------------------------------------------------------------
// Kernel 5: LIF scan over T. One thread per h (hard parallelism cap H=4096).
// ---------------------------------------------------------------------------
__global__ __launch_bounds__(64) void lif_scan(const float* __restrict__ cur, // [T,H]
                                               const float* __restrict__ m0v, // [H]
                                               float* __restrict__ agg) {     // [H]
    const int h = blockIdx.x * 64 + threadIdx.x;
    float m = m0v[h];
    float cnt = 0.f;
    float buf[2][32];
#pragma unroll
    for (int j = 0; j < 32; ++j) buf[0][j] = cur[(size_t)j * H + h];
#pragma unroll
    for (int b = 0; b < 8; ++b) {
        if (b + 1 < 8) {
#pragma unroll
            for (int j = 0; j < 32; ++j)
                buf[(b + 1) & 1][j] = cur[(size_t)((b + 1) * 32 + j) * H + h];
        }
#pragma unroll
        for (int j = 0; j < 32; ++j) {
            m = DECAY * m + buf[b & 1][j];
            if (m > THRESH) { cnt += 1.f; m = 0.f; }
        }
    }
    agg[h] = cnt * (1.0f / (float)T);
}

// ---------------------------------------------------------------------------
// Kernel 6: out_part[hy][o] = sum_{h in hy-block} agg[h] * Wout[h][o]
// ---------------------------------------------------------------------------
__global__ __launch_bounds__(256) void out_gemv(const float* __restrict__ agg,
                                                const float* __restrict__ Wout,  // [H,O]
                                                float* __restrict__ out_part) {  // [H/64, O]
    const int o = blockIdx.x * 256 + threadIdx.x;
    const int hy = blockIdx.y;
    const int h0 = hy * 64;
    float s = 0.f;
#pragma unroll 8
    for (int hh = h0; hh < h0 + 64; ++hh) {
        s += agg[hh] * Wout[(size_t)hh * O + o];
    }
    out_part[(size_t)hy * O + o] = s;
}

// ---------------------------------------------------------------------------
// Kernel 7: out[o] = b_out[o] + sum_hy out_part[hy][o]   (256 KB, L2-hot)
// ---------------------------------------------------------------------------
__global__ __launch_bounds__(256) void out_final(const float* __restrict__ out_part,
                                                 const float* __restrict__ b_out,
                                                 float* __restrict__ out) {
    const int o = blockIdx.x * 256 + threadIdx.x;
    float s = b_out[o];
#pragma unroll 8
    for (int hy = 0; hy < H / 64; ++hy) {
        s += out_part[(size_t)hy * O + o];
    }
    out[o] = s;
}

// ---------------------------------------------------------------------------
extern "C" void kernel_launch(void* const* d_in, const int* in_sizes, int n_in,
                              void* d_out, int out_size, void* d_ws, size_t ws_size,
                              hipStream_t stream) {
    const float* x     = (const float*)d_in[0];
    const float* W_in  = (const float*)d_in[1];
    const float* b_in  = (const float*)d_in[2];
    const float* W_out = (const float*)d_in[3];
    const float* b_out = (const float*)d_in[4];
    const float* m0    = (const float*)d_in[5];
    float* out = (float*)d_out;

    // ws: xbar_hi [T*I u16] | xbar_lo [T*I u16] | agg [H f32]
    //     | part [KSPLIT*T*H f32] | out_part [(H/64)*O f32]
    unsigned short* xh = (unsigned short*)d_ws;
    unsigned short* xl = xh + (size_t)T * I;
    float* agg  = (float*)(xl + (size_t)T * I);
    float* part = agg + H;
    float* out_part = part + (size_t)KSPLIT * T * H;

    const size_t need = (size_t)2 * T * I * 2 + (size_t)H * 4
                      + (size_t)KSPLIT * T * H * 4 + (size_t)(H / 64) * O * 4;
    const int fits = (ws_size >= need) ? 1 : 0;  // ws_size constant -> same path every launch

    // 1) batch mean -> bf16 hi/lo planes
    batch_reduce<<<(T * I / 4) / 256, 256, 0, stream>>>(x, xh, xl);

    dim3 g2(H / BN, KSPLIT);
    if (fits) {
        // 2) MFMA GEMM into split-K partial planes (plain stores)
        gemm_in<<<g2, 256, 0, stream>>>(xh, xl, W_in, part, 0);
        // 3) fold partials + bias into plane 0
        reduce_part<<<(T * H / 4) / 256, 256, 0, stream>>>(part, b_in, KSPLIT);
    } else {
        // fallback (small ws): atomic accumulation into a single bias-primed plane
        cur_init<<<(T * H / 4) / 256, 256, 0, stream>>>(b_in, part);
        gemm_in<<<g2, 256, 0, stream>>>(xh, xl, W_in, part, 1);
    }

    // 4) LIF scan over T -> agg[h]
    lif_scan<<<H / 64, 64, 0, stream>>>(part, m0, agg);

    // 5) out_part[hy] = agg-slice @ W_out-slice   (no atomics)
    dim3 g4(O / 256, H / 64);
    out_gemv<<<g4, 256, 0, stream>>>(agg, W_out, out_part);

    // 6) out = b_out + sum_hy out_part[hy]
    out_final<<<O / 256, 256, 0, stream>>>(out_part, b_out, out);
}